// Round 1
// baseline (227.677 us; speedup 1.0000x reference)
//
#include <hip/hip_runtime.h>
#include <math.h>

#define CC   256      // channels
#define CR   16       // reduced channels
#define SB   16384    // H*W
#define NB   16       // batch
#define LN_EPS 1e-5f

// ---------------------------------------------------------------------------
// Kernel 1: logits[b,s] = sum_c x[b,c,s] * w_mask[c] + b_mask
// grid: NB * (SB/1024) = 256 blocks, 256 threads, float4 per thread
// ---------------------------------------------------------------------------
__global__ __launch_bounds__(256) void k_logits(const float* __restrict__ x,
                                                const float* __restrict__ w_mask,
                                                const float* __restrict__ b_mask,
                                                float* __restrict__ logits) {
    const int blocksPerB = SB / 1024;
    const int b    = blockIdx.x / blocksPerB;
    const int tile = blockIdx.x % blocksPerB;
    const int s4   = tile * 1024 + threadIdx.x * 4;
    const float* xb = x + (size_t)b * CC * SB;

    float4 acc = make_float4(0.f, 0.f, 0.f, 0.f);
#pragma unroll 8
    for (int c = 0; c < CC; ++c) {
        const float w = w_mask[c];
        const float4 v = *reinterpret_cast<const float4*>(xb + (size_t)c * SB + s4);
        acc.x += v.x * w; acc.y += v.y * w; acc.z += v.z * w; acc.w += v.w * w;
    }
    const float bm = b_mask[0];
    float4 o = make_float4(acc.x + bm, acc.y + bm, acc.z + bm, acc.w + bm);
    *reinterpret_cast<float4*>(logits + (size_t)b * SB + s4) = o;
}

// ---------------------------------------------------------------------------
// Kernel 2: softmax over SB per batch. grid: NB blocks, 256 threads.
// ---------------------------------------------------------------------------
__global__ __launch_bounds__(256) void k_softmax(const float* __restrict__ logits,
                                                 float* __restrict__ attn) {
    const int b = blockIdx.x;
    const float* lb = logits + (size_t)b * SB;
    float* ab = attn + (size_t)b * SB;

    __shared__ float red[256];

    // max
    float m = -INFINITY;
    for (int i = threadIdx.x; i < SB; i += 256) m = fmaxf(m, lb[i]);
    red[threadIdx.x] = m; __syncthreads();
    for (int st = 128; st > 0; st >>= 1) {
        if (threadIdx.x < st) red[threadIdx.x] = fmaxf(red[threadIdx.x], red[threadIdx.x + st]);
        __syncthreads();
    }
    m = red[0]; __syncthreads();

    // exp + sum (store exp in attn)
    float sum = 0.f;
    for (int i = threadIdx.x; i < SB; i += 256) {
        const float e = __expf(lb[i] - m);
        ab[i] = e;
        sum += e;
    }
    red[threadIdx.x] = sum; __syncthreads();
    for (int st = 128; st > 0; st >>= 1) {
        if (threadIdx.x < st) red[threadIdx.x] += red[threadIdx.x + st];
        __syncthreads();
    }
    const float inv = 1.0f / red[0];
    __syncthreads();

    for (int i = threadIdx.x; i < SB; i += 256) ab[i] *= inv;
}

// ---------------------------------------------------------------------------
// Kernel 3: context[b,c] = sum_s x[b,c,s] * attn[b,s]
// grid: NB*CC = 4096 blocks, 256 threads, block-level reduction
// ---------------------------------------------------------------------------
__global__ __launch_bounds__(256) void k_context(const float* __restrict__ x,
                                                 const float* __restrict__ attn,
                                                 float* __restrict__ context) {
    const int b = blockIdx.x / CC;
    const int c = blockIdx.x % CC;
    const float* xb = x + ((size_t)b * CC + c) * SB;
    const float* ab = attn + (size_t)b * SB;

    float acc = 0.f;
#pragma unroll 4
    for (int i = threadIdx.x * 4; i < SB; i += 256 * 4) {
        const float4 v = *reinterpret_cast<const float4*>(xb + i);
        const float4 a = *reinterpret_cast<const float4*>(ab + i);
        acc += v.x * a.x + v.y * a.y + v.z * a.z + v.w * a.w;
    }
    __shared__ float red[256];
    red[threadIdx.x] = acc; __syncthreads();
    for (int st = 128; st > 0; st >>= 1) {
        if (threadIdx.x < st) red[threadIdx.x] += red[threadIdx.x + st];
        __syncthreads();
    }
    if (threadIdx.x == 0) context[(size_t)b * CC + c] = red[0];
}

// ---------------------------------------------------------------------------
// Kernel 4: tiny MLP: t = relu(LN(w1@ctx + b1)); add = w2@t + b2
// grid: NB blocks, 256 threads (thread = output channel)
// ---------------------------------------------------------------------------
__global__ __launch_bounds__(256) void k_mlp(const float* __restrict__ context,
                                             const float* __restrict__ w1,
                                             const float* __restrict__ b1,
                                             const float* __restrict__ ln_g,
                                             const float* __restrict__ ln_b,
                                             const float* __restrict__ w2,
                                             const float* __restrict__ b2,
                                             float* __restrict__ add) {
    const int b = blockIdx.x;
    __shared__ float ctx[CC];
    __shared__ float t[CR];
    __shared__ float tn[CR];

    ctx[threadIdx.x] = context[(size_t)b * CC + threadIdx.x];
    __syncthreads();

    if (threadIdx.x < CR) {
        float acc = b1[threadIdx.x];
        const float* w1r = w1 + (size_t)threadIdx.x * CC;
#pragma unroll 8
        for (int c = 0; c < CC; ++c) acc += w1r[c] * ctx[c];
        t[threadIdx.x] = acc;
    }
    __syncthreads();

    if (threadIdx.x == 0) {
        float mu = 0.f;
        for (int i = 0; i < CR; ++i) mu += t[i];
        mu *= (1.0f / CR);
        float var = 0.f;
        for (int i = 0; i < CR; ++i) { const float d = t[i] - mu; var += d * d; }
        var *= (1.0f / CR);
        const float inv = rsqrtf(var + LN_EPS);
        for (int i = 0; i < CR; ++i) {
            const float v = (t[i] - mu) * inv * ln_g[i] + ln_b[i];
            tn[i] = v > 0.f ? v : 0.f;
        }
    }
    __syncthreads();

    float acc = b2[threadIdx.x];
    const float* w2r = w2 + (size_t)threadIdx.x * CR;
#pragma unroll
    for (int o = 0; o < CR; ++o) acc += w2r[o] * tn[o];
    add[(size_t)b * CC + threadIdx.x] = acc;
}

// ---------------------------------------------------------------------------
// Kernel 5: out[b,c,s] = x[b,c,s] + add[b,c]
// grid: B*C*S/(256*4) = 65536 blocks, float4 per thread
// ---------------------------------------------------------------------------
__global__ __launch_bounds__(256) void k_add(const float* __restrict__ x,
                                             const float* __restrict__ add,
                                             float* __restrict__ out) {
    const size_t idx = ((size_t)blockIdx.x * 256 + threadIdx.x) * 4;
    const size_t bc = idx / SB;   // which (b,c) — 4 elems never cross a bc boundary
    const float a = add[bc];
    const float4 v = *reinterpret_cast<const float4*>(x + idx);
    float4 o = make_float4(v.x + a, v.y + a, v.z + a, v.w + a);
    *reinterpret_cast<float4*>(out + idx) = o;
}

// ---------------------------------------------------------------------------
extern "C" void kernel_launch(void* const* d_in, const int* in_sizes, int n_in,
                              void* d_out, int out_size, void* d_ws, size_t ws_size,
                              hipStream_t stream) {
    const float* x      = (const float*)d_in[0];
    const float* w_mask = (const float*)d_in[1];
    const float* b_mask = (const float*)d_in[2];
    const float* w1     = (const float*)d_in[3];
    const float* b1     = (const float*)d_in[4];
    const float* ln_g   = (const float*)d_in[5];
    const float* ln_b   = (const float*)d_in[6];
    const float* w2     = (const float*)d_in[7];
    const float* b2     = (const float*)d_in[8];
    float* out = (float*)d_out;

    // workspace layout (floats)
    float* ws      = (float*)d_ws;
    float* logits  = ws;                        // NB*SB = 262144
    float* attn    = logits + (size_t)NB * SB;  // NB*SB
    float* context = attn + (size_t)NB * SB;    // NB*CC = 4096
    float* add     = context + (size_t)NB * CC; // NB*CC

    k_logits<<<dim3(NB * (SB / 1024)), dim3(256), 0, stream>>>(x, w_mask, b_mask, logits);
    k_softmax<<<dim3(NB), dim3(256), 0, stream>>>(logits, attn);
    k_context<<<dim3(NB * CC), dim3(256), 0, stream>>>(x, attn, context);
    k_mlp<<<dim3(NB), dim3(256), 0, stream>>>(context, w1, b1, ln_g, ln_b, w2, b2, add);
    k_add<<<dim3((size_t)NB * CC * SB / 1024), dim3(256), 0, stream>>>(x, add, out);
}

// Round 2
// 177.780 us; speedup vs baseline: 1.2807x; 1.2807x over previous
//
#include <hip/hip_runtime.h>
#include <math.h>

#define CC   256      // channels
#define CR   16       // reduced channels
#define SB   16384    // H*W
#define NB   16       // batch
#define ST   64       // spatial tile per block
#define NT   (SB/ST)  // 256 tiles per batch
#define LN_EPS 1e-5f

// ---------------------------------------------------------------------------
// Kernel A (fused): for one 64-position spatial tile, stage x[all c, tile] in
// LDS (read x from HBM once), compute logits, per-tile softmax numerator, and
// per-tile partial context. Flash-style: store tile max m, tile sum of
// exp(l-m), and partial ctx_c = sum_s exp(l_s - m) x[c,s].
// b_mask is a scalar added to all logits -> cancels in softmax -> dropped.
// grid: NB*NT = 4096 blocks, 256 threads, ~67 KiB LDS (2 blocks/CU)
// ---------------------------------------------------------------------------
__global__ __launch_bounds__(256) void k_ctx_partial(const float* __restrict__ x,
                                                     const float* __restrict__ w_mask,
                                                     float* __restrict__ pc,
                                                     float* __restrict__ pm,
                                                     float* __restrict__ ps) {
    __shared__ float tile[CC * ST];   // 64 KiB: tile[c*64 + s]
    __shared__ float red[4 * ST];     // cross-wave logit partials
    __shared__ float pl[ST];          // exp(l - m) per s
    __shared__ float wm[CC];          // w_mask copy

    const int t   = threadIdx.x;
    const int bid = blockIdx.x;
    const int b   = bid / NT;
    const int s0  = (bid % NT) * ST;

    wm[t] = w_mask[t];

    // stage x tile: thread t loads rows c = (t>>4) + 16k, float4 at s=(t&15)*4
    {
        const int c0 = t >> 4;
        const int s4 = (t & 15) << 2;
        const float* xb = x + ((size_t)b * CC) * SB + s0 + s4;
#pragma unroll
        for (int k = 0; k < 16; ++k) {
            const int c = c0 + (k << 4);
            const float4 v = *reinterpret_cast<const float4*>(xb + (size_t)c * SB);
            *reinterpret_cast<float4*>(&tile[c * ST + s4]) = v;
        }
    }
    __syncthreads();

    // pass 1: logit partials. wave w covers c in [64w, 64w+64); lane s fixed.
    {
        const int s = t & 63;
        const int w = t >> 6;
        float acc = 0.f;
#pragma unroll 8
        for (int i = 0; i < 64; ++i) {
            const int c = (w << 6) + i;
            acc += tile[c * ST + s] * wm[c];
        }
        red[(w << 6) + s] = acc;
    }
    __syncthreads();

    // finalize logits + tile softmax numerator on wave 0
    if (t < 64) {
        const int s = t;
        float logit = red[s] + red[64 + s] + red[128 + s] + red[192 + s];
        float m = logit;
#pragma unroll
        for (int off = 32; off > 0; off >>= 1)
            m = fmaxf(m, __shfl_xor(m, off));
        const float p = __expf(logit - m);
        pl[s] = p;
        float sum = p;
#pragma unroll
        for (int off = 32; off > 0; off >>= 1)
            sum += __shfl_xor(sum, off);
        if (s == 0) { pm[bid] = m; ps[bid] = sum; }
    }
    __syncthreads();

    // pass 2: partial context. thread t = channel; staggered s to avoid
    // same-bank LDS reads (idx differs per lane -> 2-way max).
    {
        float acc = 0.f;
        const int base = t * ST;
#pragma unroll 8
        for (int j = 0; j < ST; ++j) {
            const int idx = (j + t) & 63;
            acc += tile[base + idx] * pl[idx];
        }
        pc[(size_t)bid * CC + t] = acc;
    }
}

// ---------------------------------------------------------------------------
// Kernel B: flash-combine across NT tiles per batch + full MLP.
// grid: NB blocks, 256 threads.
// ---------------------------------------------------------------------------
__global__ __launch_bounds__(256) void k_combine_mlp(const float* __restrict__ pc,
                                                     const float* __restrict__ pm,
                                                     const float* __restrict__ ps,
                                                     const float* __restrict__ w1,
                                                     const float* __restrict__ b1,
                                                     const float* __restrict__ ln_g,
                                                     const float* __restrict__ ln_b,
                                                     const float* __restrict__ w2,
                                                     const float* __restrict__ b2,
                                                     float* __restrict__ add) {
    const int b = blockIdx.x;
    const int t = threadIdx.x;
    __shared__ float red[256];
    __shared__ float fx[NT];
    __shared__ float ctx[CC];
    __shared__ float tbuf[CR];
    __shared__ float tn[CR];

    // global max over tile maxima
    const float m_t = pm[b * NT + t];
    red[t] = m_t; __syncthreads();
    for (int st = 128; st > 0; st >>= 1) {
        if (t < st) red[t] = fmaxf(red[t], red[t + st]);
        __syncthreads();
    }
    const float M = red[0]; __syncthreads();

    // rescale factors + global Z
    const float f = __expf(m_t - M);
    fx[t] = f;
    red[t] = ps[b * NT + t] * f; __syncthreads();
    for (int st = 128; st > 0; st >>= 1) {
        if (t < st) red[t] += red[t + st];
        __syncthreads();
    }
    const float invZ = 1.0f / red[0]; __syncthreads();

    // ctx[c] = sum_tiles pc[tile][c] * fx[tile] / Z   (coalesced over c=t)
    float acc = 0.f;
#pragma unroll 4
    for (int j = 0; j < NT; ++j)
        acc += pc[((size_t)b * NT + j) * CC + t] * fx[j];
    ctx[t] = acc * invZ;
    __syncthreads();

    // MLP: t1 = w1@ctx + b1 ; LN ; ReLU ; add = w2@t1 + b2
    if (t < CR) {
        float a = b1[t];
        const float* w1r = w1 + (size_t)t * CC;
#pragma unroll 8
        for (int c = 0; c < CC; ++c) a += w1r[c] * ctx[c];
        tbuf[t] = a;
    }
    __syncthreads();
    if (t == 0) {
        float mu = 0.f;
        for (int i = 0; i < CR; ++i) mu += tbuf[i];
        mu *= (1.0f / CR);
        float var = 0.f;
        for (int i = 0; i < CR; ++i) { const float d = tbuf[i] - mu; var += d * d; }
        var *= (1.0f / CR);
        const float inv = rsqrtf(var + LN_EPS);
        for (int i = 0; i < CR; ++i) {
            const float v = (tbuf[i] - mu) * inv * ln_g[i] + ln_b[i];
            tn[i] = v > 0.f ? v : 0.f;
        }
    }
    __syncthreads();

    float a = b2[t];
    const float* w2r = w2 + (size_t)t * CR;
#pragma unroll
    for (int o = 0; o < CR; ++o) a += w2r[o] * tn[o];
    add[(size_t)b * CC + t] = a;
}

// ---------------------------------------------------------------------------
// Kernel C: out[b,c,s] = x[b,c,s] + add[b,c]   (pure stream)
// ---------------------------------------------------------------------------
__global__ __launch_bounds__(256) void k_add(const float* __restrict__ x,
                                             const float* __restrict__ add,
                                             float* __restrict__ out) {
    const size_t idx = ((size_t)blockIdx.x * 256 + threadIdx.x) * 4;
    const size_t bc = idx / SB;
    const float a = add[bc];
    const float4 v = *reinterpret_cast<const float4*>(x + idx);
    float4 o = make_float4(v.x + a, v.y + a, v.z + a, v.w + a);
    *reinterpret_cast<float4*>(out + idx) = o;
}

// ---------------------------------------------------------------------------
extern "C" void kernel_launch(void* const* d_in, const int* in_sizes, int n_in,
                              void* d_out, int out_size, void* d_ws, size_t ws_size,
                              hipStream_t stream) {
    const float* x      = (const float*)d_in[0];
    const float* w_mask = (const float*)d_in[1];
    // d_in[2] = b_mask: scalar added to all logits; cancels in softmax.
    const float* w1     = (const float*)d_in[3];
    const float* b1     = (const float*)d_in[4];
    const float* ln_g   = (const float*)d_in[5];
    const float* ln_b   = (const float*)d_in[6];
    const float* w2     = (const float*)d_in[7];
    const float* b2     = (const float*)d_in[8];
    float* out = (float*)d_out;

    // workspace (floats): pc[NB*NT*CC]=1M, pm[NB*NT], ps[NB*NT], add[NB*CC]
    float* ws  = (float*)d_ws;
    float* pc  = ws;                              // 1,048,576
    float* pm  = pc + (size_t)NB * NT * CC;       // 4096
    float* ps  = pm + (size_t)NB * NT;            // 4096
    float* add = ps + (size_t)NB * NT;            // 4096

    k_ctx_partial<<<dim3(NB * NT), dim3(256), 0, stream>>>(x, w_mask, pc, pm, ps);
    k_combine_mlp<<<dim3(NB), dim3(256), 0, stream>>>(pc, pm, ps, w1, b1, ln_g, ln_b, w2, b2, add);
    k_add<<<dim3((size_t)NB * CC * SB / 1024), dim3(256), 0, stream>>>(x, add, out);
}

// Round 4
// 173.233 us; speedup vs baseline: 1.3143x; 1.0262x over previous
//
#include <hip/hip_runtime.h>
#include <math.h>

#define CC   256      // channels
#define CR   16       // reduced channels
#define SB   16384    // H*W
#define NB   16       // batch
#define ST   64       // spatial tile per block
#define NT   (SB/ST)  // 256 tiles per batch
#define LN_EPS 1e-5f

typedef float vfloat4 __attribute__((ext_vector_type(4)));  // builtin-compatible

// ---------------------------------------------------------------------------
// Kernel A (fused): one 64-position spatial tile per block. Stage x[:,tile]
// in LDS (single HBM read of x), folding the w_mask multiply into staging so
// logits need no second LDS pass. Then per-tile softmax numerator + partial
// context (flash-style: tile max m, tile sum exp(l-m), partial ctx).
// b_mask is a scalar on all logits -> cancels in softmax -> dropped.
// grid: NB*NT = 4096 blocks, 256 threads, ~70 KiB LDS (2 blocks/CU)
// ---------------------------------------------------------------------------
__global__ __launch_bounds__(256) void k_ctx_partial(const float* __restrict__ x,
                                                     const float* __restrict__ w_mask,
                                                     float* __restrict__ pc,
                                                     float* __restrict__ pm,
                                                     float* __restrict__ ps) {
    __shared__ float tile[CC * ST];     // 64 KiB: tile[c*64 + s]
    __shared__ float plog[64 * 17];     // padded logit partials [s][c0]
    __shared__ float pl[ST];            // exp(l - m) per s
    __shared__ float wm[CC];            // w_mask copy

    const int t   = threadIdx.x;
    const int bid = blockIdx.x;
    const int b   = bid / NT;
    const int s0  = (bid % NT) * ST;

    wm[t] = w_mask[t];
    __syncthreads();

    // stage x tile + fused logit partial: thread t loads rows c = (t>>4)+16k,
    // float4 at s=(t&15)*4, accumulating v*wm[c] as it goes.
    {
        const int c0 = t >> 4;
        const int s4 = (t & 15) << 2;
        const float* xb = x + ((size_t)b * CC) * SB + s0 + s4;
        float4 acc = make_float4(0.f, 0.f, 0.f, 0.f);
#pragma unroll
        for (int k = 0; k < 16; ++k) {
            const int c = c0 + (k << 4);
            const float4 v = *reinterpret_cast<const float4*>(xb + (size_t)c * SB);
            *reinterpret_cast<float4*>(&tile[c * ST + s4]) = v;
            const float w = wm[c];
            acc.x += v.x * w; acc.y += v.y * w; acc.z += v.z * w; acc.w += v.w * w;
        }
        plog[(s4 + 0) * 17 + c0] = acc.x;
        plog[(s4 + 1) * 17 + c0] = acc.y;
        plog[(s4 + 2) * 17 + c0] = acc.z;
        plog[(s4 + 3) * 17 + c0] = acc.w;
    }
    __syncthreads();

    // finalize logits + tile softmax numerator on wave 0
    if (t < 64) {
        const int s = t;
        float logit = 0.f;
#pragma unroll
        for (int i = 0; i < 16; ++i) logit += plog[s * 17 + i];
        float m = logit;
#pragma unroll
        for (int off = 32; off > 0; off >>= 1)
            m = fmaxf(m, __shfl_xor(m, off));
        const float p = __expf(logit - m);
        pl[s] = p;
        float sum = p;
#pragma unroll
        for (int off = 32; off > 0; off >>= 1)
            sum += __shfl_xor(sum, off);
        if (s == 0) { pm[bid] = m; ps[bid] = sum; }
    }
    __syncthreads();

    // partial context. thread t = channel; staggered s index -> conflict-free.
    {
        float acc = 0.f;
        const int base = t * ST;
#pragma unroll 8
        for (int j = 0; j < ST; ++j) {
            const int idx = (j + t) & 63;
            acc += tile[base + idx] * pl[idx];
        }
        pc[(size_t)bid * CC + t] = acc;
    }
}

// ---------------------------------------------------------------------------
// Kernel B: flash-combine across NT tiles per batch + full MLP.
// grid: NB blocks, 256 threads.
// ---------------------------------------------------------------------------
__global__ __launch_bounds__(256) void k_combine_mlp(const float* __restrict__ pc,
                                                     const float* __restrict__ pm,
                                                     const float* __restrict__ ps,
                                                     const float* __restrict__ w1,
                                                     const float* __restrict__ b1,
                                                     const float* __restrict__ ln_g,
                                                     const float* __restrict__ ln_b,
                                                     const float* __restrict__ w2,
                                                     const float* __restrict__ b2,
                                                     float* __restrict__ add) {
    const int b = blockIdx.x;
    const int t = threadIdx.x;
    __shared__ float red[256];
    __shared__ float fx[NT];
    __shared__ float ctx[CC];
    __shared__ float tbuf[CR];
    __shared__ float tn[CR];

    // global max over tile maxima
    const float m_t = pm[b * NT + t];
    red[t] = m_t; __syncthreads();
    for (int st = 128; st > 0; st >>= 1) {
        if (t < st) red[t] = fmaxf(red[t], red[t + st]);
        __syncthreads();
    }
    const float M = red[0]; __syncthreads();

    // rescale factors + global Z
    const float f = __expf(m_t - M);
    fx[t] = f;
    red[t] = ps[b * NT + t] * f; __syncthreads();
    for (int st = 128; st > 0; st >>= 1) {
        if (t < st) red[t] += red[t + st];
        __syncthreads();
    }
    const float invZ = 1.0f / red[0]; __syncthreads();

    // ctx[c] = sum_tiles pc[tile][c] * fx[tile] / Z   (coalesced over c=t)
    float acc = 0.f;
#pragma unroll 4
    for (int j = 0; j < NT; ++j)
        acc += pc[((size_t)b * NT + j) * CC + t] * fx[j];
    ctx[t] = acc * invZ;
    __syncthreads();

    // MLP: t1 = w1@ctx + b1 ; LN ; ReLU ; add = w2@t1 + b2
    if (t < CR) {
        float a = b1[t];
        const float* w1r = w1 + (size_t)t * CC;
#pragma unroll 8
        for (int c = 0; c < CC; ++c) a += w1r[c] * ctx[c];
        tbuf[t] = a;
    }
    __syncthreads();
    if (t == 0) {
        float mu = 0.f;
        for (int i = 0; i < CR; ++i) mu += tbuf[i];
        mu *= (1.0f / CR);
        float var = 0.f;
        for (int i = 0; i < CR; ++i) { const float d = tbuf[i] - mu; var += d * d; }
        var *= (1.0f / CR);
        const float inv = rsqrtf(var + LN_EPS);
        for (int i = 0; i < CR; ++i) {
            const float v = (tbuf[i] - mu) * inv * ln_g[i] + ln_b[i];
            tn[i] = v > 0.f ? v : 0.f;
        }
    }
    __syncthreads();

    float a = b2[t];
    const float* w2r = w2 + (size_t)t * CR;
#pragma unroll
    for (int o = 0; o < CR; ++o) a += w2r[o] * tn[o];
    add[(size_t)b * CC + t] = a;
}

// ---------------------------------------------------------------------------
// Kernel C: out[b,c,s] = x[b,c,s] + add[b,c]. Non-temporal out-stores keep x
// resident in Infinity Cache so the x re-read is an L3 hit, not HBM.
// 8 floats/thread. grid: NB*CC*SB/2048 = 32768 blocks.
// ---------------------------------------------------------------------------
__global__ __launch_bounds__(256) void k_add(const float* __restrict__ x,
                                             const float* __restrict__ add,
                                             float* __restrict__ out) {
    const size_t idx = ((size_t)blockIdx.x * 256 + threadIdx.x) * 8;
    const size_t bc = idx / SB;   // 8 elems never cross a (b,c) boundary
    const float a = add[bc];
    const float4 v0 = *reinterpret_cast<const float4*>(x + idx);
    const float4 v1 = *reinterpret_cast<const float4*>(x + idx + 4);
    vfloat4 o0 = {v0.x + a, v0.y + a, v0.z + a, v0.w + a};
    vfloat4 o1 = {v1.x + a, v1.y + a, v1.z + a, v1.w + a};
    __builtin_nontemporal_store(o0, reinterpret_cast<vfloat4*>(out + idx));
    __builtin_nontemporal_store(o1, reinterpret_cast<vfloat4*>(out + idx + 4));
}

// ---------------------------------------------------------------------------
extern "C" void kernel_launch(void* const* d_in, const int* in_sizes, int n_in,
                              void* d_out, int out_size, void* d_ws, size_t ws_size,
                              hipStream_t stream) {
    const float* x      = (const float*)d_in[0];
    const float* w_mask = (const float*)d_in[1];
    // d_in[2] = b_mask: scalar added to all logits; cancels in softmax.
    const float* w1     = (const float*)d_in[3];
    const float* b1     = (const float*)d_in[4];
    const float* ln_g   = (const float*)d_in[5];
    const float* ln_b   = (const float*)d_in[6];
    const float* w2     = (const float*)d_in[7];
    const float* b2     = (const float*)d_in[8];
    float* out = (float*)d_out;

    // workspace (floats): pc[NB*NT*CC]=1M, pm[NB*NT], ps[NB*NT], add[NB*CC]
    float* ws  = (float*)d_ws;
    float* pc  = ws;                              // 1,048,576
    float* pm  = pc + (size_t)NB * NT * CC;       // 4096
    float* ps  = pm + (size_t)NB * NT;            // 4096
    float* add = ps + (size_t)NB * NT;            // 4096

    k_ctx_partial<<<dim3(NB * NT), dim3(256), 0, stream>>>(x, w_mask, pc, pm, ps);
    k_combine_mlp<<<dim3(NB), dim3(256), 0, stream>>>(pc, pm, ps, w1, b1, ln_g, ln_b, w2, b2, add);
    k_add<<<dim3(NB * CC * SB / 2048), dim3(256), 0, stream>>>(x, add, out);
}